// Round 8
// baseline (129.516 us; speedup 1.0000x reference)
//
#include <hip/hip_runtime.h>

#define LN_EPS 1e-5f

// clang ext_vector types: required by __builtin_nontemporal_{load,store}
// (HIP's float4/int4 are classes and are rejected). Layout-compatible.
typedef float fv4 __attribute__((ext_vector_type(4)));
typedef int   iv4 __attribute__((ext_vector_type(4)));

// ===================== shared device helpers =====================

__device__ __forceinline__ float score_from_table(const float4 ts, const float4 td,
                                                  float sum_gw, float cbeta) {
    const float inv_d = 1.0f / 256.0f;
    float s = ts.x + td.x;
    float q = ts.y + td.y;
    float a = ts.z + td.w;   // A_lo[src] + A_hi[dst]
    float mu  = s * inv_d;
    float var = fmaf(-mu, mu, q * inv_d);
    float rs  = rsqrtf(var + LN_EPS);
    return fmaf(rs, fmaf(-mu, sum_gw, a), cbeta);
}

// Per-wave recompute of {sum(gamma*W), sum(beta*W)+bias}. gamma/beta/W are
// 1 KiB each -> L1-resident broadcast loads. Used by tier-2 kernels that
// have no workspace to hold consts.
__device__ __forceinline__ void wave_consts(const float* __restrict__ gamma,
                                            const float* __restrict__ beta,
                                            const float* __restrict__ W,
                                            const float* __restrict__ bias,
                                            float& sum_gw, float& cbeta) {
    const int lane = threadIdx.x & 63;
    const float4 gg = ((const float4*)gamma)[lane];
    const float4 ww = ((const float4*)W)[lane];
    const float4 bb = ((const float4*)beta)[lane];
    float gws = (gg.x * ww.x + gg.y * ww.y) + (gg.z * ww.z + gg.w * ww.w);
    float bws = (bb.x * ww.x + bb.y * ww.y) + (bb.z * ww.z + bb.w * ww.w);
#pragma unroll
    for (int m = 1; m < 64; m <<= 1) {
        gws += __shfl_xor(gws, m, 64);
        bws += __shfl_xor(bws, m, 64);
    }
    sum_gw = gws;
    cbeta  = bws + bias[0];
}

// ===================== Pass 1: per-node precompute =====================
// table[n] = {S, Q, A_lo, A_hi}:
//   S    = sum_j h[n][j]
//   Q    = sum_j h[n][j]^2
//   A_lo = sum_j h[n][j] * gamma[j]     * W[j]        (node as src)
//   A_hi = sum_j h[n][j] * gamma[j+128] * W[j+128]    (node as dst)
// 8 lanes per node (8 nodes/wave, 32 nodes/block): 4 float4 register
// accumulation then a 3-stage butterfly (12 ds ops per 8 nodes).
// consts may be nullptr (tier 2): then the consts block is skipped.
__global__ __launch_bounds__(256)
void node_precompute_kernel(const float* __restrict__ h,
                            const float* __restrict__ gamma,
                            const float* __restrict__ beta,
                            const float* __restrict__ W,
                            const float* __restrict__ bias,
                            float4* __restrict__ table,
                            float* __restrict__ consts,
                            int N)
{
    const int tid  = threadIdx.x;
    const int lane = tid & 63;
    const int s    = lane & 7;    // sub-lane within node (owns float4s s, s+8, s+16, s+24)
    const int g    = lane >> 3;   // node slot within wave (0..7)

    const float4* g4 = (const float4*)gamma;
    const float4* b4 = (const float4*)beta;
    const float4* w4 = (const float4*)W;

    if (consts != nullptr && blockIdx.x == 0 && tid < 64) {
        float4 gg = g4[tid], ww = w4[tid], bb = b4[tid];
        float gwsum = (gg.x * ww.x + gg.y * ww.y) + (gg.z * ww.z + gg.w * ww.w);
        float bwsum = (bb.x * ww.x + bb.y * ww.y) + (bb.z * ww.z + bb.w * ww.w);
#pragma unroll
        for (int m = 1; m < 64; m <<= 1) {
            gwsum += __shfl_xor(gwsum, m, 64);
            bwsum += __shfl_xor(bwsum, m, 64);
        }
        if (tid == 0) { consts[0] = gwsum; consts[1] = bwsum + bias[0]; }
    }

    float4 gwlo[4], gwhi[4];
#pragma unroll
    for (int k = 0; k < 4; ++k) {
        const int idx = s + 8 * k;
        float4 gl = g4[idx],      wl = w4[idx];
        float4 gh = g4[idx + 32], wh = w4[idx + 32];
        gwlo[k] = make_float4(gl.x * wl.x, gl.y * wl.y, gl.z * wl.z, gl.w * wl.w);
        gwhi[k] = make_float4(gh.x * wh.x, gh.y * wh.y, gh.z * wh.z, gh.w * wh.w);
    }

    const int waveInBlock = tid >> 6;
    const int node = (blockIdx.x * 4 + waveInBlock) * 8 + g;
    if (node >= N) return;

    const fv4* row = (const fv4*)h + (size_t)node * 32;

    float ssum = 0.0f, qsum = 0.0f, alo = 0.0f, ahi = 0.0f;
#pragma unroll
    for (int k = 0; k < 4; ++k) {
        // h is streamed exactly once -> nontemporal keeps L2 free for the table.
        fv4 v = __builtin_nontemporal_load(row + (s + 8 * k));
        ssum += (v.x + v.y) + (v.z + v.w);
        qsum = fmaf(v.x, v.x, fmaf(v.y, v.y, fmaf(v.z, v.z, fmaf(v.w, v.w, qsum))));
        alo  = fmaf(v.x, gwlo[k].x, fmaf(v.y, gwlo[k].y, fmaf(v.z, gwlo[k].z, fmaf(v.w, gwlo[k].w, alo))));
        ahi  = fmaf(v.x, gwhi[k].x, fmaf(v.y, gwhi[k].y, fmaf(v.z, gwhi[k].z, fmaf(v.w, gwhi[k].w, ahi))));
    }

#pragma unroll
    for (int m = 1; m < 8; m <<= 1) {   // xor 1,2,4 stays within the 8-lane group
        ssum += __shfl_xor(ssum, m, 64);
        qsum += __shfl_xor(qsum, m, 64);
        alo  += __shfl_xor(alo,  m, 64);
        ahi  += __shfl_xor(ahi,  m, 64);
    }
    if (s == 0) table[node] = make_float4(ssum, qsum, alo, ahi);
}

// ===================== Pass 2 (tier 1): per-edge scoring =====================
// 4 edges/thread: iv4 index loads, 8 gathers in flight, fv4 output store.
__global__ __launch_bounds__(256)
void edge_score_kernel(const int* __restrict__ src,
                       const int* __restrict__ dst,
                       const float4* __restrict__ table,
                       const float* __restrict__ consts,
                       float* __restrict__ out,
                       int E)
{
    const int t = blockIdx.x * blockDim.x + threadIdx.x;

    const float sum_gw = consts[0];
    const float cbeta  = consts[1];

    const int base = t * 4;
    if (base + 3 < E) {
        iv4 s4 = __builtin_nontemporal_load((const iv4*)src + t);
        iv4 d4 = __builtin_nontemporal_load((const iv4*)dst + t);
        // Issue all 8 gathers before any use (MLP).
        float4 ts0 = table[s4.x];
        float4 td0 = table[d4.x];
        float4 ts1 = table[s4.y];
        float4 td1 = table[d4.y];
        float4 ts2 = table[s4.z];
        float4 td2 = table[d4.z];
        float4 ts3 = table[s4.w];
        float4 td3 = table[d4.w];
        fv4 r;
        r.x = score_from_table(ts0, td0, sum_gw, cbeta);
        r.y = score_from_table(ts1, td1, sum_gw, cbeta);
        r.z = score_from_table(ts2, td2, sum_gw, cbeta);
        r.w = score_from_table(ts3, td3, sum_gw, cbeta);
        __builtin_nontemporal_store(r, (fv4*)out + t);
    } else if (base < E) {
        for (int e = base; e < E; ++e) {
            float4 ts = table[src[e]];
            float4 td = table[dst[e]];
            out[e] = score_from_table(ts, td, sum_gw, cbeta);
        }
    }
}

// ===================== Pass 2 (tier 2): table lives in out-tail =====================
// Scores edges [0, M). Table region [M, M+4N) floats of out is read-only here.
// Consts recomputed per wave (no workspace).
__global__ __launch_bounds__(256)
void edge_score_outtail_kernel(const int* __restrict__ src,
                               const int* __restrict__ dst,
                               const float4* __restrict__ table,
                               const float* __restrict__ gamma,
                               const float* __restrict__ beta,
                               const float* __restrict__ W,
                               const float* __restrict__ bias,
                               float* __restrict__ out,
                               int M)
{
    float sum_gw, cbeta;
    wave_consts(gamma, beta, W, bias, sum_gw, cbeta);

    const int t = blockIdx.x * blockDim.x + threadIdx.x;
    const int base = t * 4;
    if (base + 3 < M) {
        iv4 s4 = __builtin_nontemporal_load((const iv4*)src + t);
        iv4 d4 = __builtin_nontemporal_load((const iv4*)dst + t);
        float4 ts0 = table[s4.x];
        float4 td0 = table[d4.x];
        float4 ts1 = table[s4.y];
        float4 td1 = table[d4.y];
        float4 ts2 = table[s4.z];
        float4 td2 = table[d4.z];
        float4 ts3 = table[s4.w];
        float4 td3 = table[d4.w];
        fv4 r;
        r.x = score_from_table(ts0, td0, sum_gw, cbeta);
        r.y = score_from_table(ts1, td1, sum_gw, cbeta);
        r.z = score_from_table(ts2, td2, sum_gw, cbeta);
        r.w = score_from_table(ts3, td3, sum_gw, cbeta);
        __builtin_nontemporal_store(r, (fv4*)out + t);
    } else if (base < M) {
        for (int e = base; e < M; ++e) {
            float4 ts = table[src[e]];
            float4 td = table[dst[e]];
            out[e] = score_from_table(ts, td, sum_gw, cbeta);
        }
    }
}

// ===================== Fallback: direct-from-h scoring over [e0, E) =====================
// 16 lanes/edge, 4 edges/wave. Does NOT read the table -> safe to overwrite it.
__global__ __launch_bounds__(256)
void edge_ln_score_fallback(const float* __restrict__ h,
                            const int* __restrict__ src,
                            const int* __restrict__ dst,
                            const float* __restrict__ gamma,
                            const float* __restrict__ beta,
                            const float* __restrict__ W,
                            const float* __restrict__ bias,
                            float* __restrict__ out,
                            int e0, int E)
{
    const int tid  = threadIdx.x;
    const int lane = tid & 63;
    const int l    = lane & 15;
    const int grp  = lane >> 4;

    const int waveInBlock   = tid >> 6;
    const int wavesPerBlock = blockDim.x >> 6;
    const int gwave      = blockIdx.x * wavesPerBlock + waveInBlock;
    const int waveStride = gridDim.x * wavesPerBlock;

    const float4* g4 = (const float4*)gamma;
    const float4* b4 = (const float4*)beta;
    const float4* w4 = (const float4*)W;

    float4 gw[4];
    float gwsum = 0.0f, bwsum = 0.0f;
#pragma unroll
    for (int k = 0; k < 4; ++k) {
        float4 gg = g4[l + 16 * k];
        float4 ww = w4[l + 16 * k];
        float4 bb = b4[l + 16 * k];
        float4 r;
        r.x = gg.x * ww.x; r.y = gg.y * ww.y;
        r.z = gg.z * ww.z; r.w = gg.w * ww.w;
        gw[k] = r;
        gwsum += (r.x + r.y) + (r.z + r.w);
        bwsum += (bb.x * ww.x + bb.y * ww.y) + (bb.z * ww.z + bb.w * ww.w);
    }
#pragma unroll
    for (int m = 1; m < 64; m <<= 1) {
        gwsum += __shfl_xor(gwsum, m, 64);
        bwsum += __shfl_xor(bwsum, m, 64);
    }
    const float sum_gw = 0.25f * gwsum;
    const float cbeta  = fmaf(0.25f, bwsum, bias[0]);
    const float inv_d  = 1.0f / 256.0f;

    for (int base = e0 + gwave * 4; base < E; base += waveStride * 4) {
        int e  = base + grp;
        int ec = (e < E) ? e : (E - 1);
        int si = src[ec];
        int di = dst[ec];
        const float4* hs = (const float4*)h + (size_t)si * 32;
        const float4* hd = (const float4*)h + (size_t)di * 32;
        float4 v0 = hs[l];
        float4 v1 = hs[l + 16];
        float4 v2 = hd[l];
        float4 v3 = hd[l + 16];

        float s = ((v0.x + v0.y) + (v0.z + v0.w))
                + ((v1.x + v1.y) + (v1.z + v1.w))
                + ((v2.x + v2.y) + (v2.z + v2.w))
                + ((v3.x + v3.y) + (v3.z + v3.w));
        float q = 0.0f;
        q = fmaf(v0.x, v0.x, q); q = fmaf(v0.y, v0.y, q);
        q = fmaf(v0.z, v0.z, q); q = fmaf(v0.w, v0.w, q);
        q = fmaf(v1.x, v1.x, q); q = fmaf(v1.y, v1.y, q);
        q = fmaf(v1.z, v1.z, q); q = fmaf(v1.w, v1.w, q);
        q = fmaf(v2.x, v2.x, q); q = fmaf(v2.y, v2.y, q);
        q = fmaf(v2.z, v2.z, q); q = fmaf(v2.w, v2.w, q);
        q = fmaf(v3.x, v3.x, q); q = fmaf(v3.y, v3.y, q);
        q = fmaf(v3.z, v3.z, q); q = fmaf(v3.w, v3.w, q);
        float a = 0.0f;
        a = fmaf(v0.x, gw[0].x, a); a = fmaf(v0.y, gw[0].y, a);
        a = fmaf(v0.z, gw[0].z, a); a = fmaf(v0.w, gw[0].w, a);
        a = fmaf(v1.x, gw[1].x, a); a = fmaf(v1.y, gw[1].y, a);
        a = fmaf(v1.z, gw[1].z, a); a = fmaf(v1.w, gw[1].w, a);
        a = fmaf(v2.x, gw[2].x, a); a = fmaf(v2.y, gw[2].y, a);
        a = fmaf(v2.z, gw[2].z, a); a = fmaf(v2.w, gw[2].w, a);
        a = fmaf(v3.x, gw[3].x, a); a = fmaf(v3.y, gw[3].y, a);
        a = fmaf(v3.z, gw[3].z, a); a = fmaf(v3.w, gw[3].w, a);
#pragma unroll
        for (int m = 1; m < 16; m <<= 1) {
            s += __shfl_xor(s, m, 64);
            q += __shfl_xor(q, m, 64);
            a += __shfl_xor(a, m, 64);
        }
        float mu    = s * inv_d;
        float var   = fmaf(-mu, mu, q * inv_d);
        float rs    = rsqrtf(var + LN_EPS);
        float score = fmaf(rs, fmaf(-mu, sum_gw, a), cbeta);
        if (l == 0 && e < E) out[e] = score;
    }
}

// ===================== launcher =====================
extern "C" void kernel_launch(void* const* d_in, const int* in_sizes, int n_in,
                              void* d_out, int out_size, void* d_ws, size_t ws_size,
                              hipStream_t stream) {
    const float* h     = (const float*)d_in[0];
    const int*   src   = (const int*)d_in[1];
    const int*   dst   = (const int*)d_in[2];
    const float* gamma = (const float*)d_in[3];
    const float* beta  = (const float*)d_in[4];
    const float* W     = (const float*)d_in[5];
    const float* b     = (const float*)d_in[6];
    float* out = (float*)d_out;
    const int E = in_sizes[1];
    const int N = in_sizes[0] / 128;
    if (E <= 0 || N <= 0) return;

    const size_t ws_needed = (size_t)N * 16 + 16;

    if (ws_size >= ws_needed) {
        // ---------- Tier 1: table in workspace ----------
        float4* table  = (float4*)d_ws;
        float*  consts = (float*)((char*)d_ws + (size_t)N * 16);

        int blocks1 = (N + 31) / 32;
        hipLaunchKernelGGL(node_precompute_kernel, dim3(blocks1), dim3(256), 0, stream,
                           h, gamma, beta, W, b, table, consts, N);

        int blocks2 = ((E + 3) / 4 + 255) / 256;
        hipLaunchKernelGGL(edge_score_kernel, dim3(blocks2), dim3(256), 0, stream,
                           src, dst, table, consts, out, E);
        return;
    }

    // ---------- Tier 2: table in the tail of out ----------
    // F0 = 16B-aligned float index where the table starts inside out.
    // Edges [0, F0) are scored via the table (kernel B, writes only [0,F0)).
    // Edges [F0, E) are scored directly from h (kernel C, doesn't read table,
    // so it may overwrite it). Same-stream launches serialize A -> B -> C.
    const long long tailFloats = 4LL * N;
    const long long F0ll = ((long long)E - tailFloats) & ~3LL;
    if (F0ll >= 4) {
        const int F0 = (int)F0ll;
        float4* table = (float4*)(out + F0);

        int blocks1 = (N + 31) / 32;
        hipLaunchKernelGGL(node_precompute_kernel, dim3(blocks1), dim3(256), 0, stream,
                           h, gamma, beta, W, b, table, (float*)nullptr, N);

        int blocksB = ((F0 + 3) / 4 + 255) / 256;
        hipLaunchKernelGGL(edge_score_outtail_kernel, dim3(blocksB), dim3(256), 0, stream,
                           src, dst, table, gamma, beta, W, b, out, F0);

        hipLaunchKernelGGL(edge_ln_score_fallback, dim3(2048), dim3(256), 0, stream,
                           h, src, dst, gamma, beta, W, b, out, F0, E);
        return;
    }

    // ---------- Tier 3: tiny graph, pure fallback ----------
    hipLaunchKernelGGL(edge_ln_score_fallback, dim3(2048), dim3(256), 0, stream,
                       h, src, dst, gamma, beta, W, b, out, 0, E);
}

// Round 10
// 125.270 us; speedup vs baseline: 1.0339x; 1.0339x over previous
//
#include <hip/hip_runtime.h>

#define LN_EPS 1e-5f

// ===================== shared device helpers =====================

__device__ __forceinline__ float score_from_table(const float4 ts, const float4 td,
                                                  float sum_gw, float cbeta) {
    const float inv_d = 1.0f / 256.0f;
    float s = ts.x + td.x;
    float q = ts.y + td.y;
    float a = ts.z + td.w;   // A_lo[src] + A_hi[dst]
    float mu  = s * inv_d;
    float var = fmaf(-mu, mu, q * inv_d);
    float rs  = rsqrtf(var + LN_EPS);
    return fmaf(rs, fmaf(-mu, sum_gw, a), cbeta);
}

// Per-wave recompute of {sum(gamma*W), sum(beta*W)+bias}. gamma/beta/W are
// 1 KiB each -> L1-resident broadcast loads. Used by tier-2 kernels that
// have no workspace to hold consts.
__device__ __forceinline__ void wave_consts(const float* __restrict__ gamma,
                                            const float* __restrict__ beta,
                                            const float* __restrict__ W,
                                            const float* __restrict__ bias,
                                            float& sum_gw, float& cbeta) {
    const int lane = threadIdx.x & 63;
    const float4 gg = ((const float4*)gamma)[lane];
    const float4 ww = ((const float4*)W)[lane];
    const float4 bb = ((const float4*)beta)[lane];
    float gws = (gg.x * ww.x + gg.y * ww.y) + (gg.z * ww.z + gg.w * ww.w);
    float bws = (bb.x * ww.x + bb.y * ww.y) + (bb.z * ww.z + bb.w * ww.w);
#pragma unroll
    for (int m = 1; m < 64; m <<= 1) {
        gws += __shfl_xor(gws, m, 64);
        bws += __shfl_xor(bws, m, 64);
    }
    sum_gw = gws;
    cbeta  = bws + bias[0];
}

// ===================== Pass 1: per-node precompute =====================
// table[n] = {S, Q, A_lo, A_hi}:
//   S    = sum_j h[n][j]
//   Q    = sum_j h[n][j]^2
//   A_lo = sum_j h[n][j] * gamma[j]     * W[j]        (node as src)
//   A_hi = sum_j h[n][j] * gamma[j+128] * W[j+128]    (node as dst)
// 8 lanes per node (8 nodes/wave, 32 nodes/block): 4 float4 register
// accumulation then a 3-stage butterfly (12 ds ops per 8 nodes).
// PLAIN loads (R9: nontemporal removed — suspected cause of 1.5 TB/s
// streaming on a machine whose fill hits 6.3 TB/s in the same window).
// consts may be nullptr (tier 2): then the consts block is skipped.
__global__ __launch_bounds__(256)
void node_precompute_kernel(const float* __restrict__ h,
                            const float* __restrict__ gamma,
                            const float* __restrict__ beta,
                            const float* __restrict__ W,
                            const float* __restrict__ bias,
                            float4* __restrict__ table,
                            float* __restrict__ consts,
                            int N)
{
    const int tid  = threadIdx.x;
    const int lane = tid & 63;
    const int s    = lane & 7;    // sub-lane within node (owns float4s s, s+8, s+16, s+24)
    const int g    = lane >> 3;   // node slot within wave (0..7)

    const float4* g4 = (const float4*)gamma;
    const float4* b4 = (const float4*)beta;
    const float4* w4 = (const float4*)W;

    if (consts != nullptr && blockIdx.x == 0 && tid < 64) {
        float4 gg = g4[tid], ww = w4[tid], bb = b4[tid];
        float gwsum = (gg.x * ww.x + gg.y * ww.y) + (gg.z * ww.z + gg.w * ww.w);
        float bwsum = (bb.x * ww.x + bb.y * ww.y) + (bb.z * ww.z + bb.w * ww.w);
#pragma unroll
        for (int m = 1; m < 64; m <<= 1) {
            gwsum += __shfl_xor(gwsum, m, 64);
            bwsum += __shfl_xor(bwsum, m, 64);
        }
        if (tid == 0) { consts[0] = gwsum; consts[1] = bwsum + bias[0]; }
    }

    float4 gwlo[4], gwhi[4];
#pragma unroll
    for (int k = 0; k < 4; ++k) {
        const int idx = s + 8 * k;
        float4 gl = g4[idx],      wl = w4[idx];
        float4 gh = g4[idx + 32], wh = w4[idx + 32];
        gwlo[k] = make_float4(gl.x * wl.x, gl.y * wl.y, gl.z * wl.z, gl.w * wl.w);
        gwhi[k] = make_float4(gh.x * wh.x, gh.y * wh.y, gh.z * wh.z, gh.w * wh.w);
    }

    const int waveInBlock = tid >> 6;
    const int node = (blockIdx.x * 4 + waveInBlock) * 8 + g;
    if (node >= N) return;

    const float4* row = (const float4*)h + (size_t)node * 32;

    float ssum = 0.0f, qsum = 0.0f, alo = 0.0f, ahi = 0.0f;
#pragma unroll
    for (int k = 0; k < 4; ++k) {
        float4 v = row[s + 8 * k];
        ssum += (v.x + v.y) + (v.z + v.w);
        qsum = fmaf(v.x, v.x, fmaf(v.y, v.y, fmaf(v.z, v.z, fmaf(v.w, v.w, qsum))));
        alo  = fmaf(v.x, gwlo[k].x, fmaf(v.y, gwlo[k].y, fmaf(v.z, gwlo[k].z, fmaf(v.w, gwlo[k].w, alo))));
        ahi  = fmaf(v.x, gwhi[k].x, fmaf(v.y, gwhi[k].y, fmaf(v.z, gwhi[k].z, fmaf(v.w, gwhi[k].w, ahi))));
    }

#pragma unroll
    for (int m = 1; m < 8; m <<= 1) {   // xor 1,2,4 stays within the 8-lane group
        ssum += __shfl_xor(ssum, m, 64);
        qsum += __shfl_xor(qsum, m, 64);
        alo  += __shfl_xor(alo,  m, 64);
        ahi  += __shfl_xor(ahi,  m, 64);
    }
    if (s == 0) table[node] = make_float4(ssum, qsum, alo, ahi);
}

// ===================== Pass 2 (tier 1): per-edge scoring =====================
// R9: 8 edges/thread (was 4): int4 x2 index loads per array, 16 gathers in
// flight (gathers resolve in L3 after pass-1's L2 writeback -> more MLP
// hides the higher latency), float4 x2 output stores. Plain loads/stores.
__global__ __launch_bounds__(256)
void edge_score_kernel(const int* __restrict__ src,
                       const int* __restrict__ dst,
                       const float4* __restrict__ table,
                       const float* __restrict__ consts,
                       float* __restrict__ out,
                       int E)
{
    const int t = blockIdx.x * blockDim.x + threadIdx.x;

    const float sum_gw = consts[0];
    const float cbeta  = consts[1];

    const int base = t * 8;
    if (base + 7 < E) {
        int4 sa = ((const int4*)src)[2 * t];
        int4 sb = ((const int4*)src)[2 * t + 1];
        int4 da = ((const int4*)dst)[2 * t];
        int4 db = ((const int4*)dst)[2 * t + 1];
        // Issue all 16 gathers before any use (MLP).
        float4 ts0 = table[sa.x];
        float4 td0 = table[da.x];
        float4 ts1 = table[sa.y];
        float4 td1 = table[da.y];
        float4 ts2 = table[sa.z];
        float4 td2 = table[da.z];
        float4 ts3 = table[sa.w];
        float4 td3 = table[da.w];
        float4 ts4 = table[sb.x];
        float4 td4 = table[db.x];
        float4 ts5 = table[sb.y];
        float4 td5 = table[db.y];
        float4 ts6 = table[sb.z];
        float4 td6 = table[db.z];
        float4 ts7 = table[sb.w];
        float4 td7 = table[db.w];
        float4 r0, r1;
        r0.x = score_from_table(ts0, td0, sum_gw, cbeta);
        r0.y = score_from_table(ts1, td1, sum_gw, cbeta);
        r0.z = score_from_table(ts2, td2, sum_gw, cbeta);
        r0.w = score_from_table(ts3, td3, sum_gw, cbeta);
        r1.x = score_from_table(ts4, td4, sum_gw, cbeta);
        r1.y = score_from_table(ts5, td5, sum_gw, cbeta);
        r1.z = score_from_table(ts6, td6, sum_gw, cbeta);
        r1.w = score_from_table(ts7, td7, sum_gw, cbeta);
        ((float4*)out)[2 * t]     = r0;
        ((float4*)out)[2 * t + 1] = r1;
    } else if (base < E) {
        for (int e = base; e < E; ++e) {
            float4 ts = table[src[e]];
            float4 td = table[dst[e]];
            out[e] = score_from_table(ts, td, sum_gw, cbeta);
        }
    }
}

// ===================== Pass 2 (tier 2): table lives in out-tail =====================
// Scores edges [0, M). Table region [M, M+4N) floats of out is read-only here.
// Consts recomputed per wave (no workspace).
__global__ __launch_bounds__(256)
void edge_score_outtail_kernel(const int* __restrict__ src,
                               const int* __restrict__ dst,
                               const float4* __restrict__ table,
                               const float* __restrict__ gamma,
                               const float* __restrict__ beta,
                               const float* __restrict__ W,
                               const float* __restrict__ bias,
                               float* __restrict__ out,
                               int M)
{
    float sum_gw, cbeta;
    wave_consts(gamma, beta, W, bias, sum_gw, cbeta);

    const int t = blockIdx.x * blockDim.x + threadIdx.x;
    const int base = t * 4;
    if (base + 3 < M) {
        int4 s4 = ((const int4*)src)[t];
        int4 d4 = ((const int4*)dst)[t];
        float4 ts0 = table[s4.x];
        float4 td0 = table[d4.x];
        float4 ts1 = table[s4.y];
        float4 td1 = table[d4.y];
        float4 ts2 = table[s4.z];
        float4 td2 = table[d4.z];
        float4 ts3 = table[s4.w];
        float4 td3 = table[d4.w];
        float4 r;
        r.x = score_from_table(ts0, td0, sum_gw, cbeta);
        r.y = score_from_table(ts1, td1, sum_gw, cbeta);
        r.z = score_from_table(ts2, td2, sum_gw, cbeta);
        r.w = score_from_table(ts3, td3, sum_gw, cbeta);
        ((float4*)out)[t] = r;
    } else if (base < M) {
        for (int e = base; e < M; ++e) {
            float4 ts = table[src[e]];
            float4 td = table[dst[e]];
            out[e] = score_from_table(ts, td, sum_gw, cbeta);
        }
    }
}

// ===================== Fallback: direct-from-h scoring over [e0, E) =====================
// 16 lanes/edge, 4 edges/wave. Does NOT read the table -> safe to overwrite it.
__global__ __launch_bounds__(256)
void edge_ln_score_fallback(const float* __restrict__ h,
                            const int* __restrict__ src,
                            const int* __restrict__ dst,
                            const float* __restrict__ gamma,
                            const float* __restrict__ beta,
                            const float* __restrict__ W,
                            const float* __restrict__ bias,
                            float* __restrict__ out,
                            int e0, int E)
{
    const int tid  = threadIdx.x;
    const int lane = tid & 63;
    const int l    = lane & 15;
    const int grp  = lane >> 4;

    const int waveInBlock   = tid >> 6;
    const int wavesPerBlock = blockDim.x >> 6;
    const int gwave      = blockIdx.x * wavesPerBlock + waveInBlock;
    const int waveStride = gridDim.x * wavesPerBlock;

    const float4* g4 = (const float4*)gamma;
    const float4* b4 = (const float4*)beta;
    const float4* w4 = (const float4*)W;

    float4 gw[4];
    float gwsum = 0.0f, bwsum = 0.0f;
#pragma unroll
    for (int k = 0; k < 4; ++k) {
        float4 gg = g4[l + 16 * k];
        float4 ww = w4[l + 16 * k];
        float4 bb = b4[l + 16 * k];
        float4 r;
        r.x = gg.x * ww.x; r.y = gg.y * ww.y;
        r.z = gg.z * ww.z; r.w = gg.w * ww.w;
        gw[k] = r;
        gwsum += (r.x + r.y) + (r.z + r.w);
        bwsum += (bb.x * ww.x + bb.y * ww.y) + (bb.z * ww.z + bb.w * ww.w);
    }
#pragma unroll
    for (int m = 1; m < 64; m <<= 1) {
        gwsum += __shfl_xor(gwsum, m, 64);
        bwsum += __shfl_xor(bwsum, m, 64);
    }
    const float sum_gw = 0.25f * gwsum;
    const float cbeta  = fmaf(0.25f, bwsum, bias[0]);
    const float inv_d  = 1.0f / 256.0f;

    for (int base = e0 + gwave * 4; base < E; base += waveStride * 4) {
        int e  = base + grp;
        int ec = (e < E) ? e : (E - 1);
        int si = src[ec];
        int di = dst[ec];
        const float4* hs = (const float4*)h + (size_t)si * 32;
        const float4* hd = (const float4*)h + (size_t)di * 32;
        float4 v0 = hs[l];
        float4 v1 = hs[l + 16];
        float4 v2 = hd[l];
        float4 v3 = hd[l + 16];

        float s = ((v0.x + v0.y) + (v0.z + v0.w))
                + ((v1.x + v1.y) + (v1.z + v1.w))
                + ((v2.x + v2.y) + (v2.z + v2.w))
                + ((v3.x + v3.y) + (v3.z + v3.w));
        float q = 0.0f;
        q = fmaf(v0.x, v0.x, q); q = fmaf(v0.y, v0.y, q);
        q = fmaf(v0.z, v0.z, q); q = fmaf(v0.w, v0.w, q);
        q = fmaf(v1.x, v1.x, q); q = fmaf(v1.y, v1.y, q);
        q = fmaf(v1.z, v1.z, q); q = fmaf(v1.w, v1.w, q);
        q = fmaf(v2.x, v2.x, q); q = fmaf(v2.y, v2.y, q);
        q = fmaf(v2.z, v2.z, q); q = fmaf(v2.w, v2.w, q);
        q = fmaf(v3.x, v3.x, q); q = fmaf(v3.y, v3.y, q);
        q = fmaf(v3.z, v3.z, q); q = fmaf(v3.w, v3.w, q);
        float a = 0.0f;
        a = fmaf(v0.x, gw[0].x, a); a = fmaf(v0.y, gw[0].y, a);
        a = fmaf(v0.z, gw[0].z, a); a = fmaf(v0.w, gw[0].w, a);
        a = fmaf(v1.x, gw[1].x, a); a = fmaf(v1.y, gw[1].y, a);
        a = fmaf(v1.z, gw[1].z, a); a = fmaf(v1.w, gw[1].w, a);
        a = fmaf(v2.x, gw[2].x, a); a = fmaf(v2.y, gw[2].y, a);
        a = fmaf(v2.z, gw[2].z, a); a = fmaf(v2.w, gw[2].w, a);
        a = fmaf(v3.x, gw[3].x, a); a = fmaf(v3.y, gw[3].y, a);
        a = fmaf(v3.z, gw[3].z, a); a = fmaf(v3.w, gw[3].w, a);
#pragma unroll
        for (int m = 1; m < 16; m <<= 1) {
            s += __shfl_xor(s, m, 64);
            q += __shfl_xor(q, m, 64);
            a += __shfl_xor(a, m, 64);
        }
        float mu    = s * inv_d;
        float var   = fmaf(-mu, mu, q * inv_d);
        float rs    = rsqrtf(var + LN_EPS);
        float score = fmaf(rs, fmaf(-mu, sum_gw, a), cbeta);
        if (l == 0 && e < E) out[e] = score;
    }
}

// ===================== launcher =====================
extern "C" void kernel_launch(void* const* d_in, const int* in_sizes, int n_in,
                              void* d_out, int out_size, void* d_ws, size_t ws_size,
                              hipStream_t stream) {
    const float* h     = (const float*)d_in[0];
    const int*   src   = (const int*)d_in[1];
    const int*   dst   = (const int*)d_in[2];
    const float* gamma = (const float*)d_in[3];
    const float* beta  = (const float*)d_in[4];
    const float* W     = (const float*)d_in[5];
    const float* b     = (const float*)d_in[6];
    float* out = (float*)d_out;
    const int E = in_sizes[1];
    const int N = in_sizes[0] / 128;
    if (E <= 0 || N <= 0) return;

    const size_t ws_needed = (size_t)N * 16 + 16;

    if (ws_size >= ws_needed) {
        // ---------- Tier 1: table in workspace ----------
        float4* table  = (float4*)d_ws;
        float*  consts = (float*)((char*)d_ws + (size_t)N * 16);

        int blocks1 = (N + 31) / 32;
        hipLaunchKernelGGL(node_precompute_kernel, dim3(blocks1), dim3(256), 0, stream,
                           h, gamma, beta, W, b, table, consts, N);

        int blocks2 = ((E + 7) / 8 + 255) / 256;
        hipLaunchKernelGGL(edge_score_kernel, dim3(blocks2), dim3(256), 0, stream,
                           src, dst, table, consts, out, E);
        return;
    }

    // ---------- Tier 2: table in the tail of out ----------
    // F0 = 16B-aligned float index where the table starts inside out.
    // Edges [0, F0) are scored via the table (kernel B, writes only [0,F0)).
    // Edges [F0, E) are scored directly from h (kernel C, doesn't read table,
    // so it may overwrite it). Same-stream launches serialize A -> B -> C.
    const long long tailFloats = 4LL * N;
    const long long F0ll = ((long long)E - tailFloats) & ~3LL;
    if (F0ll >= 4) {
        const int F0 = (int)F0ll;
        float4* table = (float4*)(out + F0);

        int blocks1 = (N + 31) / 32;
        hipLaunchKernelGGL(node_precompute_kernel, dim3(blocks1), dim3(256), 0, stream,
                           h, gamma, beta, W, b, table, (float*)nullptr, N);

        int blocksB = ((F0 + 3) / 4 + 255) / 256;
        hipLaunchKernelGGL(edge_score_outtail_kernel, dim3(blocksB), dim3(256), 0, stream,
                           src, dst, table, gamma, beta, W, b, out, F0);

        hipLaunchKernelGGL(edge_ln_score_fallback, dim3(2048), dim3(256), 0, stream,
                           h, src, dst, gamma, beta, W, b, out, F0, E);
        return;
    }

    // ---------- Tier 3: tiny graph, pure fallback ----------
    hipLaunchKernelGGL(edge_ln_score_fallback, dim3(2048), dim3(256), 0, stream,
                       h, src, dst, gamma, beta, W, b, out, 0, E);
}